// Round 2
// baseline (291.630 us; speedup 1.0000x reference)
//
#include <hip/hip_runtime.h>

// Problem constants (from reference): B=16, S=4096, D=256, MAXDUR=8
#define BATCH 16
#define SEQ   4096
#define DIM   256

#define ROWS_PER_WAVE 4
// 4 waves/block, ROWS_PER_WAVE source rows per wave
#define SCATTER_BLOCKS (BATCH * SEQ / (4 * ROWS_PER_WAVE))
#define TAILC 128                          // tail-zero blocks per batch

// native clang vector type — accepted by __builtin_nontemporal_{load,store}
typedef float f32x4 __attribute__((ext_vector_type(4)));

// ---------------------------------------------------------------------------
// Kernel A: per-batch inclusive scan of durations -> csum[B*S], totals[B]
// One block per batch; 1024 threads * 4 elements = 4096.
// ---------------------------------------------------------------------------
__global__ __launch_bounds__(1024) void scan_kernel(const int* __restrict__ dims,
                                                    int* __restrict__ csum,
                                                    int* __restrict__ totals) {
    __shared__ int wsum[16];
    const int b    = blockIdx.x;
    const int tid  = threadIdx.x;      // 0..1023
    const int lane = tid & 63;
    const int wave = tid >> 6;         // 0..15

    // 4 consecutive durations per thread (int4, 16B aligned)
    const int4 dv = ((const int4*)(dims + b * SEQ))[tid];
    const int p0 = dv.x;
    const int p1 = p0 + dv.y;
    const int p2 = p1 + dv.z;
    const int p3 = p2 + dv.w;          // thread-local inclusive sums
    int v = p3;                        // thread total

    // wave-level inclusive scan of thread totals (64 lanes)
    #pragma unroll
    for (int off = 1; off < 64; off <<= 1) {
        int n = __shfl_up(v, off, 64);
        if (lane >= off) v += n;
    }
    if (lane == 63) wsum[wave] = v;    // wave total
    __syncthreads();

    if (tid == 0) {                    // serial exclusive scan over 16 wave totals
        int run = 0;
        #pragma unroll
        for (int i = 0; i < 16; ++i) { int t = wsum[i]; wsum[i] = run; run += t; }
        totals[b] = run;               // full batch total
    }
    __syncthreads();

    const int excl = wsum[wave] + (v - p3);   // block-exclusive prefix of this thread
    int4 o;
    o.x = excl + p0; o.y = excl + p1; o.z = excl + p2; o.w = excl + p3;
    // cached store (NOT nontemporal): consumed by expand_kernel right after
    ((int4*)(csum + b * SEQ))[tid] = o;
}

// ---------------------------------------------------------------------------
// Kernel B: scatter-expand + tail zero-fill.
// Blocks [0, SCATTER_BLOCKS): one wave per 4 CONSECUTIVE source rows.
//   Wave-uniform int4 csum read gives {end0..end3}; one scalar read gives
//   start0. Up to 4 independent predicated nontemporal row loads (4KB MLP),
//   then up to 28 predicated cached stores (avg 14KB/wave).
// Blocks [SCATTER_BLOCKS, +B*TAILC): zero rows [totals[b], T).
//
// R1: output stores CACHED (nt stores cost +8.5us — L2 write aggregation wins).
// R2: 4 rows/wave — raise per-wave MLP 4x, cut wave count 73k->16k, shrink
//     cnt-variance imbalance (sigma/mu 65% -> 33%).
// ---------------------------------------------------------------------------
__global__ __launch_bounds__(256) void expand_kernel(const float* __restrict__ x,
                                                     const int* __restrict__ csum,
                                                     const int* __restrict__ totals,
                                                     float* __restrict__ out,
                                                     int T) {
    const int lane = threadIdx.x & 63;
    const int wave = threadIdx.x >> 6;

    if (blockIdx.x < SCATTER_BLOCKS) {
        const int wv = blockIdx.x * 4 + wave;     // wave id
        const int r0 = wv * ROWS_PER_WAVE;        // first source row, multiple of 4
        const int b  = r0 >> 12;                  // / SEQ
        const int s0 = r0 & (SEQ - 1);

        // inclusive csum for rows r0..r0+3 (wave-uniform, 16B aligned)
        const int4 ce = *(const int4*)(csum + r0);
        const int start0 = (s0 == 0) ? 0 : csum[r0 - 1];

        const int st0 = start0, en0 = ce.x;
        const int st1 = ce.x,   en1 = ce.y;
        const int st2 = ce.y,   en2 = ce.z;
        const int st3 = ce.z,   en3 = ce.w;
        const int c0 = en0 - st0, c1 = en1 - st1, c2 = en2 - st2, c3 = en3 - st3;

        // up to 4 independent row loads (predicated, wave-uniform branches)
        const f32x4* xs = (const f32x4*)x + (size_t)r0 * (DIM / 4) + lane;
        f32x4 row0, row1, row2, row3;
        if (c0 > 0) row0 = __builtin_nontemporal_load(xs + 0 * (DIM / 4));
        if (c1 > 0) row1 = __builtin_nontemporal_load(xs + 1 * (DIM / 4));
        if (c2 > 0) row2 = __builtin_nontemporal_load(xs + 2 * (DIM / 4));
        if (c3 > 0) row3 = __builtin_nontemporal_load(xs + 3 * (DIM / 4));

        f32x4* const ob = (f32x4*)out + (size_t)b * T * (DIM / 4) + lane;

        #pragma unroll
        for (int j = 0; j < 7; ++j)
            if (j < c0) ob[(size_t)(st0 + j) * (DIM / 4)] = row0;
        for (int j = 7; j < c0; ++j) ob[(size_t)(st0 + j) * (DIM / 4)] = row0;

        #pragma unroll
        for (int j = 0; j < 7; ++j)
            if (j < c1) ob[(size_t)(st1 + j) * (DIM / 4)] = row1;
        for (int j = 7; j < c1; ++j) ob[(size_t)(st1 + j) * (DIM / 4)] = row1;

        #pragma unroll
        for (int j = 0; j < 7; ++j)
            if (j < c2) ob[(size_t)(st2 + j) * (DIM / 4)] = row2;
        for (int j = 7; j < c2; ++j) ob[(size_t)(st2 + j) * (DIM / 4)] = row2;

        #pragma unroll
        for (int j = 0; j < 7; ++j)
            if (j < c3) ob[(size_t)(st3 + j) * (DIM / 4)] = row3;
        for (int j = 7; j < c3; ++j) ob[(size_t)(st3 + j) * (DIM / 4)] = row3;
    } else {
        const int idx   = blockIdx.x - SCATTER_BLOCKS;
        const int b     = idx / TAILC;
        const int chunk = idx % TAILC;
        const int t0    = totals[b];
        const f32x4 z   = {0.f, 0.f, 0.f, 0.f};
        // TAILC blocks * 4 waves stride over tail rows of batch b, 2x unrolled
        for (int t = t0 + chunk * 4 + wave; t < T; t += 2 * TAILC * 4) {
            ((f32x4*)out)[((size_t)b * T + t) * (DIM / 4) + lane] = z;
            const int t2 = t + TAILC * 4;
            if (t2 < T)
                ((f32x4*)out)[((size_t)b * T + t2) * (DIM / 4) + lane] = z;
        }
    }
}

extern "C" void kernel_launch(void* const* d_in, const int* in_sizes, int n_in,
                              void* d_out, int out_size, void* d_ws, size_t ws_size,
                              hipStream_t stream) {
    const float* x    = (const float*)d_in[0];   // [B,S,D] float32
    const int*   dims = (const int*)d_in[1];     // [B,S,1] int32
    float*       out  = (float*)d_out;           // [B,T,D] float32

    const int T = out_size / (BATCH * DIM);      // padded output length

    int* totals = (int*)d_ws;                    // B ints
    int* csum   = totals + 64;                   // 256B offset keeps 16B alignment

    scan_kernel<<<BATCH, 1024, 0, stream>>>(dims, csum, totals);
    expand_kernel<<<SCATTER_BLOCKS + BATCH * TAILC, 256, 0, stream>>>(
        x, csum, totals, out, T);
}